// Round 2
// 64.924 us; speedup vs baseline: 1.0247x; 1.0247x over previous
//
#include <hip/hip_runtime.h>
#include <math.h>

// Problem constants (fixed by reference)
constexpr int N_ = 4, P_ = 64, Z_ = 32, Y_ = 128, X_ = 128;
constexpr float EPSF = 1e-8f;
constexpr float INV2S2 = 0.125f;   // 1/(2*sigma^2), sigma = 2

typedef short v8s __attribute__((ext_vector_type(8)));  // 8 bf16 (4 VGPRs)
typedef float v4f __attribute__((ext_vector_type(4)));  // MFMA C/D

// fp32 -> bf16 (RNE). bf16 keeps fp32's exponent: no far-field flush.
__device__ __forceinline__ short bf16(float f) {
    unsigned u = __float_as_uint(f);
    u = u + 0x7fffu + ((u >> 16) & 1u);
    return (short)(u >> 16);
}

// ---------------------------------------------------------------------------
// MFMA main kernel. Grid: 256 blocks = (n, z, y-half); 512 threads = 8 waves.
// R10 change vs the 4-wave version: with 256 blocks on 256 CUs the old kernel
// ran at exactly 1 wave/SIMD -> every phase of the serial chain was fully
// latency-exposed (the chip-wide throughput work is ~2 us; the rest was
// stalls). 8 waves = 2 waves/SIMD halves per-thread chain length and lets
// co-resident waves cover each other's stalls. MFMA tile count per block is
// unchanged (tiles are partitioned across waves, 8 MFMAs/wave per GEMM);
// only the analytic A-fragments are duplicated 2x (cheap exps).
// Also: the 16 logits loads are hoisted to the very top of the kernel
// (consumed ~1500 cycles later in the W phase) so HBM latency hides under
// kx-table + a1 + GEMM1 instead of serializing after GEMM1.
//
// Per block (y-slab of 64 rows x full 128 x):
//   GEMM1 (mfma_f32_16x16x32_bf16): denom[y][x] = sum_p kzy[y][p]*kx[p][x]
//          M=64 (y: 4 tiles, wave w owns mt=w&3), N=128 (x: 8 tiles, wave w
//          owns the 4 tiles of half nh=w>>2), K=64 (p: 2 mfma steps).
//   W[y][x] = sigmoid(logit)/max(denom,EPS), bf16 -> LDS (layout transform).
//   GEMM2: D2[p][y] = sum_x kx[p][x]*W[y][x]
//          M=64 (p: 4 tiles, wave owns pt=w&3), N=64 (y: wave owns the 2
//          tiles of half yh=w>>2), K=128 (x: 4 mfma steps).
//   macc[p] += sum_y kzy[y][p]*D2[p][y]  (two y-halves combined via psum).
// Fragment layouts (HW-verified): A[m=lane&15][k=quad*8+j],
// B[k=quad*8+j][n=lane&15], C/D: col=lane&15, row=quad*4+reg.
// kx/W tiles live in LDS with XOR chunk swizzle (chunk' = chunk ^ (row &
// (nchunks-1))) so fragment reads (row stride 128/256 B) spread across banks.
// ---------------------------------------------------------------------------
__global__ __launch_bounds__(512) void k_main(const float* __restrict__ logits,
                                              const float* __restrict__ pts,
                                              float* __restrict__ part) {
    const int b = blockIdx.x;          // [n:2][z:5][yh:1]
    const int n  = b >> 6;
    const int z  = (b >> 1) & 31;
    const int y0 = (b & 1) * 64;

    const int tid  = threadIdx.x;
    const int lane = tid & 63;
    const int w    = tid >> 6;         // wave 0..7
    const int m    = lane & 15;        // row/col-in-tile index
    const int quad = lane >> 4;        // 0..3
    const int mt   = w & 3;            // GEMM1 M-tile (y group of 16)
    const int nh   = w >> 2;           // GEMM1 N-half (x tiles nh*4..nh*4+3)
    const int pt   = w & 3;            // GEMM2 M-tile (p group of 16)
    const int yh   = w >> 2;           // GEMM2 N-half (y tiles yh*2..yh*2+1)

    __shared__ float ptsn[192];        // pts[n] = [64][3]
    __shared__ short kxTB[128 * 64];   // [x][p] bf16, 8-chunk XOR swizzle
    __shared__ short WB[64 * 128];     // [y-local][x] bf16, 16-chunk swizzle
    __shared__ float psum[2][64];      // per-y-half partials, combined at end

    // Hoisted logits loads: issue 16 dwords NOW, consume in the W phase
    // (after GEMM1). Each logit read exactly once grid-wide; 16-lane groups
    // read contiguous 64 B segments.
    const float* lb = logits + (size_t)((n * Z_ + z) * Y_ + y0) * X_;
    float lgs[4][4];
    #pragma unroll
    for (int nt = 0; nt < 4; ++nt)
        #pragma unroll
        for (int reg = 0; reg < 4; ++reg)
            lgs[nt][reg] = lb[(mt * 16 + quad * 4 + reg) * 128 + (nh * 4 + nt) * 16 + m];

    if (tid < 192) ptsn[tid] = pts[n * 192 + tid];
    __syncthreads();

    // kx table: 8192 exps / 512 threads = 16 iters. Store at swizzled chunk.
    for (int i = tid; i < 128 * 64; i += 512) {
        int x = i >> 6, p = i & 63;
        float dx = (float)x - ptsn[p * 3 + 2];
        float e = __expf(-dx * dx * INV2S2);
        kxTB[x * 64 + (((p >> 3) ^ (x & 7)) * 8) + (p & 7)] = bf16(e);
    }

    // GEMM1 A-frags (kzy rows) analytically: 16 exps/lane (waves w, w+4
    // duplicate — cheap). quad-uniform ptsn reads broadcast.
    v8s a1[2];
    {
        float yv = (float)(y0 + mt * 16 + m);
        #pragma unroll
        for (int ks = 0; ks < 2; ++ks) {
            #pragma unroll
            for (int j = 0; j < 8; ++j) {
                int p = ks * 32 + quad * 8 + j;
                float dz = (float)z - ptsn[p * 3 + 0];
                float dy = yv - ptsn[p * 3 + 1];
                a1[ks][j] = bf16(__expf(-(dz * dz + dy * dy) * INV2S2));
            }
        }
    }
    __syncthreads();                   // kxTB ready

    // GEMM1: wave w -> M-tile mt, N-tiles nh*4..nh*4+3, K = 2 mfma steps.
    v4f acc1[4];
    #pragma unroll
    for (int nt = 0; nt < 4; ++nt) acc1[nt] = (v4f)(0.f);
    #pragma unroll
    for (int ks = 0; ks < 2; ++ks) {
        #pragma unroll
        for (int nt = 0; nt < 4; ++nt) {
            int row = (nh * 4 + nt) * 16 + m;   // x
            int c = ks * 4 + quad;              // p-chunk
            v8s bf = *(const v8s*)&kxTB[row * 64 + ((c ^ (row & 7)) * 8)];
            acc1[nt] = __builtin_amdgcn_mfma_f32_16x16x32_bf16(a1[ks], bf, acc1[nt], 0, 0, 0);
        }
    }

    // W = sigmoid(logit)*rcp(max(denom,EPS)) -> WB (bf16, swizzled).
    // lgs loaded at kernel start — latency long gone.
    #pragma unroll
    for (int nt = 0; nt < 4; ++nt) {
        #pragma unroll
        for (int reg = 0; reg < 4; ++reg) {
            int yl = mt * 16 + quad * 4 + reg;
            int x  = (nh * 4 + nt) * 16 + m;
            float wv = 1.0f / ((1.0f + __expf(-lgs[nt][reg])) *
                               fmaxf(acc1[nt][reg], EPSF));
            WB[yl * 128 + (((x >> 3) ^ (yl & 15)) * 8) + (x & 7)] = bf16(wv);
        }
    }

    // GEMM2 A-frags (kx row p = pt*16+m) analytically: 16 exps/lane.
    v8s a2[4];
    {
        float px = ptsn[(pt * 16 + m) * 3 + 2];
        #pragma unroll
        for (int ks = 0; ks < 4; ++ks) {
            #pragma unroll
            for (int j = 0; j < 8; ++j) {
                float dx = (float)(ks * 32 + quad * 8 + j) - px;
                a2[ks][j] = bf16(__expf(-dx * dx * INV2S2));
            }
        }
    }
    __syncthreads();                   // WB ready

    // GEMM2: wave w -> M-tile pt (p), N-tiles yh*2..yh*2+1 (y), K = 4 steps.
    v4f acc2[2];
    acc2[0] = (v4f)(0.f);
    acc2[1] = (v4f)(0.f);
    #pragma unroll
    for (int ks = 0; ks < 4; ++ks) {
        #pragma unroll
        for (int nt = 0; nt < 2; ++nt) {
            int row = (yh * 2 + nt) * 16 + m;   // y-local
            int c = ks * 4 + quad;              // x-chunk
            v8s bf = *(const v8s*)&WB[row * 128 + ((c ^ (row & 15)) * 8)];
            acc2[nt] = __builtin_amdgcn_mfma_f32_16x16x32_bf16(a2[ks], bf, acc2[nt], 0, 0, 0);
        }
    }

    // Epilogue: s[reg] = sum_nt kzy[y][p]*D2[p][y]; p = pt*16+quad*4+reg,
    // y = y0+(yh*2+nt)*16+m. kzy analytic (8 exps/lane).
    float s[4] = {0.f, 0.f, 0.f, 0.f};
    #pragma unroll
    for (int reg = 0; reg < 4; ++reg) {
        int p = pt * 16 + quad * 4 + reg;
        float pz = ptsn[p * 3 + 0], py = ptsn[p * 3 + 1];
        float dz = (float)z - pz;
        #pragma unroll
        for (int nt = 0; nt < 2; ++nt) {
            float dy = (float)(y0 + (yh * 2 + nt) * 16 + m) - py;
            float kzy = __expf(-(dz * dz + dy * dy) * INV2S2);
            s[reg] = fmaf(acc2[nt][reg], kzy, s[reg]);
        }
    }
    // Reduce over the 16 y-lanes (low 4 lane bits).
    #pragma unroll
    for (int reg = 0; reg < 4; ++reg)
        #pragma unroll
        for (int off = 1; off < 16; off <<= 1)
            s[reg] += __shfl_xor(s[reg], off, 64);
    if (m == 0) {
        #pragma unroll
        for (int reg = 0; reg < 4; ++reg)
            psum[yh][pt * 16 + quad * 4 + reg] = s[reg];
    }
    __syncthreads();
    if (tid < 64) part[b * 64 + tid] = psum[0][tid] + psum[1][tid];
}

// ---------------------------------------------------------------------------
// Finish: m[n][p] = sum of that n's 64 block-partials; loss = mean(-log(...)).
// 1 block x 1024 threads: 4 threads per (n,p), 16 partials each, LDS combine.
// (R8 proved the in-kernel fence finish costs +23 us — keep 2 dispatches.)
// ---------------------------------------------------------------------------
__global__ __launch_bounds__(1024) void k_finish(const float* __restrict__ part,
                                                 float* __restrict__ out) {
    const int t = threadIdx.x;
    const int pair = t & 255;          // (n,p)
    const int quarter = t >> 8;        // 16-block slice
    const int n = pair >> 6, p = pair & 63;

    const float* base = part + (size_t)(n * 64 + quarter * 16) * 64 + p;
    float s0 = 0.f, s1 = 0.f, s2 = 0.f, s3 = 0.f;
    #pragma unroll
    for (int j = 0; j < 16; j += 4) {
        s0 += base[(j + 0) * 64];
        s1 += base[(j + 1) * 64];
        s2 += base[(j + 2) * 64];
        s3 += base[(j + 3) * 64];
    }
    __shared__ float red[4][256];
    red[quarter][pair] = (s0 + s1) + (s2 + s3);
    __syncthreads();

    if (t < 256) {
        const float mv = (red[0][t] + red[1][t]) + (red[2][t] + red[3][t]);
        float l = -logf(fmaxf(mv, EPSF));
        #pragma unroll
        for (int off = 32; off > 0; off >>= 1) l += __shfl_xor(l, off, 64);
        __shared__ float red2[4];
        if ((t & 63) == 0) red2[t >> 6] = l;
        __syncthreads();
        if (t == 0) out[0] = (red2[0] + red2[1] + red2[2] + red2[3]) * (1.0f / 256.0f);
    }
}

extern "C" void kernel_launch(void* const* d_in, const int* in_sizes, int n_in,
                              void* d_out, int out_size, void* d_ws, size_t ws_size,
                              hipStream_t stream) {
    const float* logits = (const float*)d_in[0];  // [4,1,32,128,128] fp32
    const float* pts    = (const float*)d_in[1];  // [4,64,3] fp32
    float* part = (float*)d_ws;                   // 256*64 floats = 64 KB
    float* out  = (float*)d_out;                  // scalar fp32

    k_main<<<dim3(256), dim3(512), 0, stream>>>(logits, pts, part);
    k_finish<<<dim3(1), dim3(1024), 0, stream>>>(part, out);
}